// Round 6
// baseline (1682.134 us; speedup 1.0000x reference)
//
#include <hip/hip_runtime.h>
#include <cstdint>

typedef __attribute__((ext_vector_type(8))) short short8;
typedef __attribute__((ext_vector_type(4))) float f32x4;

#define LOG2E 1.44269504088896340736f
#define SHIFT 64.0f

__device__ __forceinline__ unsigned short f2bf(float x) {
  union { float f; unsigned u; } c; c.f = x;
  unsigned r = c.u + 0x7fffu + ((c.u >> 16) & 1u);
  return (unsigned short)(r >> 16);
}

// async global->LDS 16B/lane: HW writes lane l's data at lptr + l*16
__device__ __forceinline__ void gl2lds16(const void* g, void* l) {
  __builtin_amdgcn_global_load_lds((const __attribute__((address_space(1))) void*)g,
                                   (__attribute__((address_space(3))) void*)l, 16, 0, 0);
}

// ---------------------------------------------------------------------------
// K0: fp32 -> bf16 weight conversion (Wq, Wk)
// ---------------------------------------------------------------------------
__global__ void cvt_bf16(const float* __restrict__ src, unsigned short* __restrict__ dst, int n4) {
  int i = blockIdx.x * 256 + threadIdx.x;
  if (i >= n4) return;
  float4 v = ((const float4*)src)[i];
  ushort4 o;
  o.x = f2bf(v.x); o.y = f2bf(v.y); o.z = f2bf(v.z); o.w = f2bf(v.w);
  ((ushort4*)dst)[i] = o;
}

// ---------------------------------------------------------------------------
// Attention machinery v5: register-resident operand + distance-3 stream ring.
//   Resident tile staged in two 32KB halves (rows 0-63, then 64-127) into
//   pool[0,32K), hoisted to VGPRs by the owning wave pair, area then dead.
//   Row r of a half lives at (r-h*64)*512; granule pos p holds source granule
//   (p&24)|((p&7)^(r&7)) -- r&7 invariant under the 64-row shift.
//   Stream: 4 x 8KB ring at pool+32768; chunk m -> buf m&3; chunk s+3 staged
//   FIRST in step s (stage drains ~free at the step-end __syncthreads).
// ---------------------------------------------------------------------------
__device__ __forceinline__ void stage_resident_half(char* lds, const char* src, int w, int lane) {
  const int p = lane & 31;
  const int rlo = lane >> 5;  // 0..1
#pragma unroll
  for (int it = 0; it < 8; ++it) {
    const int rl = w * 16 + it * 2 + rlo;
    const int gs = (p & 24) | ((p & 7) ^ (rl & 7));
    gl2lds16(src + (size_t)rl * 512 + gs * 16, lds + (w * 8 + it) * 1024);
  }
}

__device__ __forceinline__ void stage_stream(char* buf, const char* srcbase, int roff0, int roff1,
                                             int w) {
  gl2lds16(srcbase + roff0, buf + w * 1024);
  gl2lds16(srcbase + roff1, buf + 4096 + w * 1024);
}

// ---------------------------------------------------------------------------
// K2: row sums -> linv_i = 1 / sum_j exp2(S_ij*log2e - 64).  WG = (b,128 rows).
// Q resident in regs; K streams; next-chunk fragments prefetched (bfr dbuf).
// ---------------------------------------------------------------------------
__global__ __launch_bounds__(256, 2) void attn_rowsum(
    const unsigned short* __restrict__ qt, const unsigned short* __restrict__ kt,
    float* __restrict__ linv) {
  extern __shared__ char pool[];  // [0,32K) resident half; [32K,64K) 4x8K ring
  const int b = blockIdx.y, i0 = blockIdx.x * 128;
  const int t = threadIdx.x, w = t >> 6, lane = t & 63, q = lane >> 4, ln = lane & 15;
  const int ihalf = w >> 1, jhalf = w & 1;
  const char* qres = (const char*)(qt + ((size_t)b * 4096 + i0) * 256);
  const char* kb = (const char*)(kt + (size_t)b * 4096 * 256);
  const int rr0 = w * 16 + (lane >> 2);
  const int gsS = (lane & 3) ^ ((lane >> 3) & 3);
  const int roff0 = rr0 * 512 + gsS * 16;
  const int roff1 = (64 + rr0) * 512 + gsS * 16;
  const int bRow = jhalf * 4096 + ln * 64 + (q ^ ((ln >> 1) & 3)) * 16;
  char* sbuf = pool + 32768;
  float lacc[4][4] = {};
  short8 ares[8][4], bfr[2][4];

  // ---- prologue ----
  stage_resident_half(pool, qres, w, lane);                 // rows 0..63 (ihalf 0)
  stage_stream(sbuf, kb, roff0, roff1, w);                  // chunk 0 -> buf 0
  stage_stream(sbuf + 8192, kb + 64, roff0, roff1, w);      // chunk 1 -> buf 1
  stage_stream(sbuf + 16384, kb + 128, roff0, roff1, w);    // chunk 2 -> buf 2
  __syncthreads();
  if (ihalf == 0) {
#pragma unroll
    for (int c = 0; c < 8; ++c) {
      const int posA = ((4 * c) & 24) | ((4 * (c & 1) + q) ^ (ln & 7));
#pragma unroll
      for (int mt = 0; mt < 4; ++mt)
        ares[c][mt] = *(const short8*)(pool + (mt * 16 + ln) * 512 + posA * 16);
    }
  }
#pragma unroll
  for (int nt = 0; nt < 4; ++nt) bfr[0][nt] = *(const short8*)(sbuf + bRow + nt * 1024);
  __syncthreads();                       // hoist/prefetch reads done before restage
  stage_resident_half(pool, qres + 64 * 512, w, lane);      // rows 64..127 (ihalf 1)
  __syncthreads();
  if (ihalf == 1) {
#pragma unroll
    for (int c = 0; c < 8; ++c) {
      const int posA = ((4 * c) & 24) | ((4 * (c & 1) + q) ^ (ln & 7));
#pragma unroll
      for (int mt = 0; mt < 4; ++mt)
        ares[c][mt] = *(const short8*)(pool + (mt * 16 + ln) * 512 + posA * 16);
    }
  }
  // (no barrier needed: loop touches only sbuf; resident area is dead hereafter)

#pragma unroll 1
  for (int jt = 0; jt < 32; ++jt) {
    f32x4 acc[4][4] = {};
#pragma unroll
    for (int c = 0; c < 8; ++c) {
      const int s = jt * 8 + c;
      if (s < 253) {
        const int m = s + 3;
        stage_stream(sbuf + (m & 3) * 8192, kb + (size_t)(m >> 3) * 65536 + (m & 7) * 64,
                     roff0, roff1, w);
      }
      if (s < 255) {
        const char* Bn = sbuf + ((s + 1) & 3) * 8192;
#pragma unroll
        for (int nt = 0; nt < 4; ++nt)
          bfr[(c + 1) & 1][nt] = *(const short8*)(Bn + bRow + nt * 1024);
      }
#pragma unroll
      for (int mt = 0; mt < 4; ++mt)
#pragma unroll
        for (int nt = 0; nt < 4; ++nt)
          acc[mt][nt] = __builtin_amdgcn_mfma_f32_16x16x32_bf16(ares[c][mt], bfr[c & 1][nt],
                                                                acc[mt][nt], 0, 0, 0);
      __syncthreads();
    }
    // epilogue (register-only): per-row partial sumexp over this 128-j tile
#pragma unroll
    for (int mt = 0; mt < 4; ++mt)
#pragma unroll
      for (int r = 0; r < 4; ++r) {
        float e = exp2f(acc[mt][0][r] * LOG2E - SHIFT) + exp2f(acc[mt][1][r] * LOG2E - SHIFT)
                + exp2f(acc[mt][2][r] * LOG2E - SHIFT) + exp2f(acc[mt][3][r] * LOG2E - SHIFT);
        e += __shfl_xor(e, 1); e += __shfl_xor(e, 2);
        e += __shfl_xor(e, 4); e += __shfl_xor(e, 8);
        lacc[mt][r] += e;
      }
  }
  // cross-wave reduce in the dead resident area
  float* lred = (float*)pool;
  if (ln == 0) {
#pragma unroll
    for (int mt = 0; mt < 4; ++mt)
#pragma unroll
      for (int r = 0; r < 4; ++r)
        lred[jhalf * 128 + ihalf * 64 + mt * 16 + q * 4 + r] = lacc[mt][r];
  }
  __syncthreads();
  if (t < 128) linv[b * 4096 + i0 + t] = 1.0f / (lred[t] + lred[128 + t]);
}

// ---------------------------------------------------------------------------
// K3: column sums  s_j = sum_i exp2(S_ij*log2e - 64) * linv_i.  WG=(b,128 cols).
// K resident in regs; Q streams distance-3 (no frag prefetch: VGPR headroom).
// ---------------------------------------------------------------------------
__global__ __launch_bounds__(256, 2) void attn_colsum(
    const unsigned short* __restrict__ qt, const unsigned short* __restrict__ kt,
    const float* __restrict__ linv, float* __restrict__ s_col) {
  extern __shared__ char pool[];  // [0,32K) resident half; [32K,64K) 4x8K ring
  const int b = blockIdx.y, j0 = blockIdx.x * 128;
  const int t = threadIdx.x, w = t >> 6, lane = t & 63, q = lane >> 4, ln = lane & 15;
  const int ihalf = w >> 1, jhalf = w & 1;
  const char* kres = (const char*)(kt + ((size_t)b * 4096 + j0) * 256);
  const char* qb = (const char*)(qt + (size_t)b * 4096 * 256);
  const int rr0 = w * 16 + (lane >> 2);
  const int gsS = (lane & 3) ^ ((lane >> 3) & 3);
  const int roff0 = rr0 * 512 + gsS * 16;
  const int roff1 = (64 + rr0) * 512 + gsS * 16;
  const int aRow = ihalf * 4096 + ln * 64 + (q ^ ((ln >> 1) & 3)) * 16;
  char* sbuf = pool + 32768;
  float scacc[4] = {};
  short8 bres[8][4];

  // ---- prologue ----
  stage_resident_half(pool, kres, w, lane);                 // rows 0..63 (jhalf 0)
  stage_stream(sbuf, qb, roff0, roff1, w);                  // chunk 0 -> buf 0
  stage_stream(sbuf + 8192, qb + 64, roff0, roff1, w);      // chunk 1 -> buf 1
  stage_stream(sbuf + 16384, qb + 128, roff0, roff1, w);    // chunk 2 -> buf 2
  __syncthreads();
  if (jhalf == 0) {
#pragma unroll
    for (int c = 0; c < 8; ++c) {
      const int posB = ((4 * c) & 24) | ((4 * (c & 1) + q) ^ (ln & 7));
#pragma unroll
      for (int nt = 0; nt < 4; ++nt)
        bres[c][nt] = *(const short8*)(pool + (nt * 16 + ln) * 512 + posB * 16);
    }
  }
  __syncthreads();
  stage_resident_half(pool, kres + 64 * 512, w, lane);      // rows 64..127 (jhalf 1)
  __syncthreads();
  if (jhalf == 1) {
#pragma unroll
    for (int c = 0; c < 8; ++c) {
      const int posB = ((4 * c) & 24) | ((4 * (c & 1) + q) ^ (ln & 7));
#pragma unroll
      for (int nt = 0; nt < 4; ++nt)
        bres[c][nt] = *(const short8*)(pool + (nt * 16 + ln) * 512 + posB * 16);
    }
  }

#pragma unroll 1
  for (int it = 0; it < 32; ++it) {
    // per-row 1/l for this q-tile (broadcast across ln; issued early)
    const float4* lp = (const float4*)(linv + (size_t)b * 4096 + it * 128 + ihalf * 64 + q * 4);
    float4 lv[4];
#pragma unroll
    for (int mt = 0; mt < 4; ++mt) lv[mt] = lp[mt * 4];

    f32x4 acc[4][4] = {};
#pragma unroll
    for (int c = 0; c < 8; ++c) {
      const int s = it * 8 + c;
      if (s < 253) {
        const int m = s + 3;
        stage_stream(sbuf + (m & 3) * 8192, qb + (size_t)(m >> 3) * 65536 + (m & 7) * 64,
                     roff0, roff1, w);
      }
      const char* A = sbuf + (s & 3) * 8192;
      short8 af[4];
#pragma unroll
      for (int mt = 0; mt < 4; ++mt) af[mt] = *(const short8*)(A + aRow + mt * 1024);
#pragma unroll
      for (int mt = 0; mt < 4; ++mt)
#pragma unroll
        for (int nt = 0; nt < 4; ++nt)
          acc[mt][nt] =
              __builtin_amdgcn_mfma_f32_16x16x32_bf16(af[mt], bres[c][nt], acc[mt][nt], 0, 0, 0);
      __syncthreads();
    }
#pragma unroll
    for (int nt = 0; nt < 4; ++nt) {
      float v = 0.f;
#pragma unroll
      for (int mt = 0; mt < 4; ++mt) {
        v += exp2f(acc[mt][nt][0] * LOG2E - SHIFT) * lv[mt].x;
        v += exp2f(acc[mt][nt][1] * LOG2E - SHIFT) * lv[mt].y;
        v += exp2f(acc[mt][nt][2] * LOG2E - SHIFT) * lv[mt].z;
        v += exp2f(acc[mt][nt][3] * LOG2E - SHIFT) * lv[mt].w;
      }
      v += __shfl_xor(v, 16); v += __shfl_xor(v, 32);
      scacc[nt] += v;
    }
  }
  float* sred = (float*)pool;
  if (q == 0) {
#pragma unroll
    for (int nt = 0; nt < 4; ++nt)
      sred[ihalf * 128 + jhalf * 64 + nt * 16 + ln] = scacc[nt];
  }
  __syncthreads();
  if (t < 128) s_col[b * 4096 + j0 + t] = sred[t] + sred[128 + t];
}

// ---------------------------------------------------------------------------
// K1 v2: projection  Out[b][sp][co] = sum_ci In[b][ci][sp]*W[co][ci] + bias[co]
// 128 sp x 256 co tile, 4 waves each 64sp x 2x64co (acc[2][4][4]).
// ---------------------------------------------------------------------------
__global__ __launch_bounds__(256, 2) void proj2_kernel(
    const float* __restrict__ In, const unsigned short* __restrict__ Wbf,
    const float* __restrict__ bias, unsigned short* __restrict__ Out, int Kdim) {
  __shared__ char Alds[128 * 144];   // 18 KB
  __shared__ char Blds[256 * 128];   // 32 KB
  const int b = blockIdx.y, sp0 = blockIdx.x * 128;
  const int t = threadIdx.x, w = t >> 6, lane = t & 63, q = lane >> 4, ln = lane & 15;
  const int shalf = w >> 1;          // sp half (0..1)
  const int cq = w & 1;              // co quarter-within-half (0..1)
  const size_t wrow = (size_t)Kdim * 2;  // W row stride in bytes
  f32x4 acc[2][4][4] = {};
  const int nch = Kdim >> 6;

  const int brow0 = w * 8 + (lane >> 3);            // + i*32 per issue
  const int bgs = (lane & 7) ^ (lane >> 3);
  const int cp = t >> 3;             // ci pair 0..31
  const int spg = t & 7;             // sp group of 16

#pragma unroll 1
  for (int ch = 0; ch < nch; ++ch) {
    const int ci0 = ch * 64;
    // ---- stage B: W[256 co][64 ci] via global_load_lds, swizzled source ----
    const char* wsrc = (const char*)Wbf + (size_t)ci0 * 2 + bgs * 16;
#pragma unroll
    for (int i = 0; i < 8; ++i)
      gl2lds16(wsrc + (size_t)(brow0 + i * 32) * wrow, Blds + i * 4096 + w * 1024);
    // ---- stage A: transpose-convert In[64 ci][128 sp] -> Alds[sp][ci] ----
    {
      const float* r0 = In + ((size_t)b * Kdim + ci0 + 2 * cp) * 4096 + sp0 + spg * 16;
      const float* r1 = r0 + 4096;
#pragma unroll
      for (int h = 0; h < 2; ++h) {
        float4 a0 = *(const float4*)(r0 + h * 8);
        float4 a1 = *(const float4*)(r0 + h * 8 + 4);
        float4 b0 = *(const float4*)(r1 + h * 8);
        float4 b1 = *(const float4*)(r1 + h * 8 + 4);
        float va[8] = {a0.x, a0.y, a0.z, a0.w, a1.x, a1.y, a1.z, a1.w};
        float vb[8] = {b0.x, b0.y, b0.z, b0.w, b1.x, b1.y, b1.z, b1.w};
#pragma unroll
        for (int e = 0; e < 8; ++e) {
          const int spl = spg * 16 + h * 8 + e;
          const int colb = (cp << 2) ^ (((spl >> 4) & 7) << 4);
          unsigned u0 = f2bf(va[e]), u1 = f2bf(vb[e]);
          *(unsigned*)(Alds + spl * 144 + colb) = u0 | (u1 << 16);
        }
      }
    }
    __syncthreads();
    // ---- MFMA: 2 ks x (4 A-frags, 2 co-halves x 4 B-frags x 16 mfma) ----
#pragma unroll
    for (int ks = 0; ks < 2; ++ks) {
      short8 af[4], bfr[4];
#pragma unroll
      for (int mt = 0; mt < 4; ++mt) {
        const int row = shalf * 64 + mt * 16 + ln;
        const int colr = (ks * 64 + q * 16) ^ (((row >> 4) & 7) << 4);
        af[mt] = *(const short8*)(Alds + row * 144 + colr);
      }
#pragma unroll
      for (int cb = 0; cb < 2; ++cb) {
#pragma unroll
        for (int nt = 0; nt < 4; ++nt) {
          const int row = cb * 128 + cq * 64 + nt * 16 + ln;
          const int pos = (ks * 4 + q) ^ (ln & 7);
          bfr[nt] = *(const short8*)(Blds + row * 128 + pos * 16);
        }
#pragma unroll
        for (int mt = 0; mt < 4; ++mt)
#pragma unroll
          for (int nt = 0; nt < 4; ++nt)
            acc[cb][mt][nt] =
                __builtin_amdgcn_mfma_f32_16x16x32_bf16(af[mt], bfr[nt], acc[cb][mt][nt], 0, 0, 0);
      }
    }
    __syncthreads();
  }
  // ---- epilogue ----
#pragma unroll
  for (int cb = 0; cb < 2; ++cb)
#pragma unroll
    for (int nt = 0; nt < 4; ++nt) {
      const int co = cb * 128 + cq * 64 + nt * 16 + ln;
      const float bv = bias[co];
#pragma unroll
      for (int mt = 0; mt < 4; ++mt)
#pragma unroll
        for (int r = 0; r < 4; ++r) {
          const int sp = sp0 + shalf * 64 + mt * 16 + q * 4 + r;
          Out[((size_t)b * 4096 + sp) * 256 + co] = f2bf(acc[cb][mt][nt][r] + bv);
        }
    }
}

// ---------------------------------------------------------------------------
// sbar[b] = sum_n s[b][n] / 4096
// ---------------------------------------------------------------------------
__global__ void sbar_kernel(const float* __restrict__ s_col, float* __restrict__ sbar) {
  const int b = blockIdx.x, t = threadIdx.x;
  float v = 0.f;
  for (int k = 0; k < 16; ++k) v += s_col[b * 4096 + t + 256 * k];
  for (int m = 1; m < 64; m <<= 1) v += __shfl_xor(v, m);
  __shared__ float red[4];
  if ((t & 63) == 0) red[t >> 6] = v;
  __syncthreads();
  if (t == 0) sbar[b] = (red[0] + red[1] + red[2] + red[3]) * (1.f / 4096.f);
}

// ---------------------------------------------------------------------------
// K4 v2: pooling, one wave = one contiguous channel row (fully coalesced).
// ---------------------------------------------------------------------------
__global__ __launch_bounds__(256) void pool2_kernel(
    const float* __restrict__ img, const float* __restrict__ pc2d,
    const float* __restrict__ s_col, float* __restrict__ u_pool,
    float* __restrict__ imean, float* __restrict__ t_pool) {
  const int t = threadIdx.x, w = t >> 6, lane = t & 63;
  const int gid = blockIdx.x * 4 + w;
  const int b = gid / 2304, c = gid - b * 2304;
  const bool isimg = c < 256;
  const float4* row4 = isimg
      ? (const float4*)(img + ((size_t)b * 256 + c) * 4096)
      : (const float4*)(pc2d + ((size_t)b * 2048 + (c - 256)) * 4096);
  const float4* s4 = (const float4*)(s_col + (size_t)b * 4096);
  float accd = 0.f, accs = 0.f;
#pragma unroll
  for (int kk = 0; kk < 16; ++kk) {
    float4 x = row4[lane + 64 * kk];
    float4 sv = s4[lane + 64 * kk];
    accd += x.x * sv.x + x.y * sv.y + x.z * sv.z + x.w * sv.w;
    accs += x.x + x.y + x.z + x.w;
  }
#pragma unroll
  for (int m = 1; m < 64; m <<= 1) {
    accd += __shfl_xor(accd, m);
    accs += __shfl_xor(accs, m);
  }
  if (lane == 0) {
    if (isimg) {
      u_pool[b * 256 + c] = accd * (1.f / 4096.f);
      imean[b * 256 + c] = accs * (1.f / 4096.f);
    } else {
      t_pool[b * 2048 + (c - 256)] = accd * (1.f / 4096.f);
    }
  }
}

// ---------------------------------------------------------------------------
// img_feat -> fused[0:256]
// ---------------------------------------------------------------------------
__global__ void imgfeat_kernel(const float* __restrict__ Wvi, const float* __restrict__ bvi,
                               const float* __restrict__ gamma1, const float* __restrict__ u_pool,
                               const float* __restrict__ imean, const float* __restrict__ sbar,
                               float* __restrict__ fused) {
  const int t = threadIdx.x;
  const int co = blockIdx.x * 64 + (t >> 2), j = t & 3;
  float acc[16];
#pragma unroll
  for (int b = 0; b < 16; ++b) acc[b] = 0.f;
  const float4* w4 = (const float4*)(Wvi + (size_t)co * 256);
  for (int kk = 0; kk < 16; ++kk) {
    float4 wv = w4[j + 4 * kk];
#pragma unroll
    for (int b = 0; b < 16; ++b) {
      float4 uv = ((const float4*)(u_pool + b * 256))[j + 4 * kk];
      acc[b] += wv.x * uv.x + wv.y * uv.y + wv.z * uv.z + wv.w * uv.w;
    }
  }
#pragma unroll
  for (int b = 0; b < 16; ++b) { acc[b] += __shfl_xor(acc[b], 1); acc[b] += __shfl_xor(acc[b], 2); }
  if (j == 0) {
    float g = gamma1[0], bv = bvi[co];
#pragma unroll
    for (int b = 0; b < 16; ++b)
      fused[b * 2304 + co] = g * (acc[b] + bv * sbar[b]) + imean[b * 256 + co];
  }
}

// ---------------------------------------------------------------------------
// pc_feat -> fused[256:2304]
// ---------------------------------------------------------------------------
__global__ void pcfeat_kernel(const float* __restrict__ Wvp, const float* __restrict__ bvp,
                              const float* __restrict__ t_pool, const float* __restrict__ sbar,
                              float* __restrict__ fused) {
  const int t = threadIdx.x;
  const int co = blockIdx.x * 64 + (t >> 2), j = t & 3;
  float acc[16];
#pragma unroll
  for (int b = 0; b < 16; ++b) acc[b] = 0.f;
  const float4* w4 = (const float4*)(Wvp + (size_t)co * 2048);
  for (int kk = 0; kk < 128; ++kk) {
    float4 wv = w4[j + 4 * kk];
#pragma unroll
    for (int b = 0; b < 16; ++b) {
      float4 tv = ((const float4*)(t_pool + b * 2048))[j + 4 * kk];
      acc[b] += wv.x * tv.x + wv.y * tv.y + wv.z * tv.z + wv.w * tv.w;
    }
  }
#pragma unroll
  for (int b = 0; b < 16; ++b) { acc[b] += __shfl_xor(acc[b], 1); acc[b] += __shfl_xor(acc[b], 2); }
  if (j == 0) {
    float bv = bvp[co];
#pragma unroll
    for (int b = 0; b < 16; ++b)
      fused[b * 2304 + 256 + co] = acc[b] + bv * sbar[b];
  }
}

// ---------------------------------------------------------------------------
// h = relu(fused @ W1^T + b1)
// ---------------------------------------------------------------------------
__global__ void head1_kernel(const float* __restrict__ W1, const float* __restrict__ b1,
                             const float* __restrict__ fused, float* __restrict__ h) {
  const int t = threadIdx.x;
  const int o = blockIdx.x * 64 + (t >> 2), j = t & 3;
  float acc[16];
#pragma unroll
  for (int b = 0; b < 16; ++b) acc[b] = 0.f;
  const float4* w4 = (const float4*)(W1 + (size_t)o * 2304);
  for (int kk = 0; kk < 144; ++kk) {
    float4 wv = w4[j + 4 * kk];
#pragma unroll
    for (int b = 0; b < 16; ++b) {
      float4 fv = ((const float4*)(fused + b * 2304))[j + 4 * kk];
      acc[b] += wv.x * fv.x + wv.y * fv.y + wv.z * fv.z + wv.w * fv.w;
    }
  }
#pragma unroll
  for (int b = 0; b < 16; ++b) { acc[b] += __shfl_xor(acc[b], 1); acc[b] += __shfl_xor(acc[b], 2); }
  if (j == 0) {
    float bv = b1[o];
#pragma unroll
    for (int b = 0; b < 16; ++b) h[b * 1024 + o] = fmaxf(acc[b] + bv, 0.f);
  }
}

// ---------------------------------------------------------------------------
// logits + log_softmax -> out[b][40]
// ---------------------------------------------------------------------------
__global__ void head2_kernel(const float* __restrict__ W2, const float* __restrict__ b2,
                             const float* __restrict__ h, float* __restrict__ out) {
  const int b = blockIdx.x, t = threadIdx.x;
  __shared__ float logit[40];
  __shared__ float red[4];
  float4 hv = ((const float4*)(h + b * 1024))[t];
  for (int c = 0; c < 40; ++c) {
    float4 wv = ((const float4*)(W2 + (size_t)c * 1024))[t];
    float p = wv.x * hv.x + wv.y * hv.y + wv.z * hv.z + wv.w * hv.w;
    for (int m = 1; m < 64; m <<= 1) p += __shfl_xor(p, m);
    if ((t & 63) == 0) red[t >> 6] = p;
    __syncthreads();
    if (t == 0) logit[c] = red[0] + red[1] + red[2] + red[3] + b2[c];
    __syncthreads();
  }
  if (t == 0) {
    float mx = -1e30f;
    for (int c = 0; c < 40; ++c) mx = fmaxf(mx, logit[c]);
    float s = 0.f;
    for (int c = 0; c < 40; ++c) s += expf(logit[c] - mx);
    float ls = logf(s);
    for (int c = 0; c < 40; ++c) out[b * 40 + c] = logit[c] - mx - ls;
  }
}

// ---------------------------------------------------------------------------
extern "C" void kernel_launch(void* const* d_in, const int* in_sizes, int n_in,
                              void* d_out, int out_size, void* d_ws, size_t ws_size,
                              hipStream_t stream) {
  (void)in_sizes; (void)n_in; (void)out_size; (void)ws_size;
  const float* img    = (const float*)d_in[0];
  const float* pc2d   = (const float*)d_in[1];
  const float* Wq     = (const float*)d_in[2];
  const float* bq     = (const float*)d_in[3];
  const float* Wk     = (const float*)d_in[4];
  const float* bk     = (const float*)d_in[5];
  const float* Wvi    = (const float*)d_in[6];
  const float* bvi    = (const float*)d_in[7];
  const float* Wvp    = (const float*)d_in[8];
  const float* bvp    = (const float*)d_in[9];
  const float* gamma1 = (const float*)d_in[10];
  const float* W1     = (const float*)d_in[11];
  const float* b1     = (const float*)d_in[12];
  const float* W2     = (const float*)d_in[13];
  const float* b2     = (const float*)d_in[14];

  char* ws = (char*)d_ws;
  unsigned short* q_t   = (unsigned short*)(ws + 0);          // 32 MB
  unsigned short* k_t   = (unsigned short*)(ws + 33554432);   // 32 MB
  unsigned short* wq_bf = (unsigned short*)(ws + 67108864);   // 128 KB
  unsigned short* wk_bf = (unsigned short*)(ws + 67239936);   // 1 MB
  float* linv   = (float*)(ws + 68288512);                    // 16*4096 f32
  float* s_col  = (float*)(ws + 68812800);
  float* sbar   = (float*)(ws + 69074944);
  float* u_pool = (float*)(ws + 69075008);
  float* imean  = (float*)(ws + 69091392);
  float* t_pool = (float*)(ws + 69107776);
  float* fusedb = (float*)(ws + 69238848);
  float* h_buf  = (float*)(ws + 69386304);

  hipFuncSetAttribute((const void*)attn_rowsum, hipFuncAttributeMaxDynamicSharedMemorySize, 65536);
  hipFuncSetAttribute((const void*)attn_colsum, hipFuncAttributeMaxDynamicSharedMemorySize, 65536);

  cvt_bf16<<<dim3(64), dim3(256), 0, stream>>>(Wq, wq_bf, 16384);
  cvt_bf16<<<dim3(512), dim3(256), 0, stream>>>(Wk, wk_bf, 131072);

  proj2_kernel<<<dim3(32, 16), dim3(256), 0, stream>>>(img, wq_bf, bq, q_t, 256);
  proj2_kernel<<<dim3(32, 16), dim3(256), 0, stream>>>(pc2d, wk_bf, bk, k_t, 2048);

  attn_rowsum<<<dim3(32, 16), dim3(256), 65536, stream>>>(q_t, k_t, linv);
  attn_colsum<<<dim3(32, 16), dim3(256), 65536, stream>>>(q_t, k_t, linv, s_col);

  sbar_kernel<<<dim3(16), dim3(256), 0, stream>>>(s_col, sbar);
  pool2_kernel<<<dim3(9216), dim3(256), 0, stream>>>(img, pc2d, s_col, u_pool, imean, t_pool);

  imgfeat_kernel<<<dim3(4), dim3(256), 0, stream>>>(Wvi, bvi, gamma1, u_pool, imean, sbar, fusedb);
  pcfeat_kernel<<<dim3(32), dim3(256), 0, stream>>>(Wvp, bvp, t_pool, sbar, fusedb);

  head1_kernel<<<dim3(16), dim3(256), 0, stream>>>(W1, b1, fusedb, h_buf);
  head2_kernel<<<dim3(16), dim3(256), 0, stream>>>(W2, b2, h_buf, (float*)d_out);
}

// Round 7
// 1586.179 us; speedup vs baseline: 1.0605x; 1.0605x over previous
//
#include <hip/hip_runtime.h>
#include <cstdint>

typedef __attribute__((ext_vector_type(8))) short short8;
typedef __attribute__((ext_vector_type(4))) float f32x4;

#define LOG2E 1.44269504088896340736f
#define SHIFT 64.0f

__device__ __forceinline__ unsigned short f2bf(float x) {
  union { float f; unsigned u; } c; c.f = x;
  unsigned r = c.u + 0x7fffu + ((c.u >> 16) & 1u);
  return (unsigned short)(r >> 16);
}

// async global->LDS 16B/lane: HW writes lane l's data at lptr + l*16
__device__ __forceinline__ void gl2lds16(const void* g, void* l) {
  __builtin_amdgcn_global_load_lds((const __attribute__((address_space(1))) void*)g,
                                   (__attribute__((address_space(3))) void*)l, 16, 0, 0);
}

// ---------------------------------------------------------------------------
// K0: fp32 -> bf16 weight conversion, both weights in one launch.
// blocks [0,64): Wq (16384 float4), blocks [64,576): Wk (131072 float4)
// ---------------------------------------------------------------------------
__global__ void cvt_bf16_2(const float* __restrict__ srcq, unsigned short* __restrict__ dstq,
                           const float* __restrict__ srck, unsigned short* __restrict__ dstk) {
  const int blk = blockIdx.x;
  const float* src;
  unsigned short* dst;
  int i;
  if (blk < 64) {
    src = srcq; dst = dstq; i = blk * 256 + threadIdx.x;
  } else {
    src = srck; dst = dstk; i = (blk - 64) * 256 + threadIdx.x;
  }
  float4 v = ((const float4*)src)[i];
  ushort4 o;
  o.x = f2bf(v.x); o.y = f2bf(v.y); o.z = f2bf(v.z); o.w = f2bf(v.w);
  ((ushort4*)dst)[i] = o;
}

// ---------------------------------------------------------------------------
// Attention machinery v3/v5-best: operand-resident tiling + register-hoisted
// resident fragments, 2-buffer stream with stage-after-read ordering.
//   Resident tile: 128 rows x 256 ch bf16 (64 KB), row pitch 512B.
//     Stored 16B-granule position p (0..31) of row r holds SOURCE granule
//     (p&24) | ((p&7) ^ (r&7)).
//   Stream tile: 128 rows x 32 ch (8 KB) double-buffered, row pitch 64B.
//     Stored position p (0..3) of row r holds src granule p ^ ((r>>1)&3).
// ---------------------------------------------------------------------------
__device__ __forceinline__ void stage_resident(char* ldsbase, const char* src, int w, int lane) {
  const int p = lane & 31;
  const int rlo = lane >> 5;  // 0..1
#pragma unroll
  for (int it = 0; it < 16; ++it) {
    const int r = w * 32 + it * 2 + rlo;
    const int gs = (p & 24) | ((p & 7) ^ (r & 7));
    gl2lds16(src + (size_t)r * 512 + gs * 16, ldsbase + (w * 16 + it) * 1024);
  }
}

__device__ __forceinline__ void stage_stream(char* buf, const char* srcbase, int roff0, int roff1,
                                             int w) {
  gl2lds16(srcbase + roff0, buf + w * 1024);
  gl2lds16(srcbase + roff1, buf + 4096 + w * 1024);
}

// ---------------------------------------------------------------------------
// K2: row sums -> linv_i = 1 / sum_j exp2(S_ij*log2e - 64).  WG = (b,128 rows).
// Q-tile resident (regs); K streams in 8KB chunks.
// ---------------------------------------------------------------------------
__global__ __launch_bounds__(256, 2) void attn_rowsum(
    const unsigned short* __restrict__ qt, const unsigned short* __restrict__ kt,
    float* __restrict__ linv) {
  extern __shared__ char pool[];  // [0,64K) resident Q; [64K,80K) stream K dbuf
  const int b = blockIdx.y, i0 = blockIdx.x * 128;
  const int t = threadIdx.x, w = t >> 6, lane = t & 63, q = lane >> 4, ln = lane & 15;
  const int ihalf = w >> 1, jhalf = w & 1;
  const char* qres = (const char*)(qt + ((size_t)b * 4096 + i0) * 256);
  const char* kb = (const char*)(kt + (size_t)b * 4096 * 256);
  // stream staging per-lane constants
  const int rr0 = w * 16 + (lane >> 2);
  const int gsS = (lane & 3) ^ ((lane >> 3) & 3);
  const int roff0 = rr0 * 512 + gsS * 16;
  const int roff1 = (64 + rr0) * 512 + gsS * 16;
  // fragment read bases (bytes)
  const int aRow = (ihalf * 64 + ln) * 512;
  const int bRow = jhalf * 4096 + ln * 64 + (q ^ ((ln >> 1) & 3)) * 16;
  float lacc[4][4] = {};

  stage_resident(pool, qres, w, lane);
  stage_stream(pool + 65536, kb, roff0, roff1, w);
  __syncthreads();

  // hoist resident Q fragments into registers (compile-time indices -> VGPRs)
  short8 ares[8][4];
#pragma unroll
  for (int c = 0; c < 8; ++c) {
    const int posA = ((4 * c) & 24) | ((4 * (c & 1) + q) ^ (ln & 7));
#pragma unroll
    for (int mt = 0; mt < 4; ++mt)
      ares[c][mt] = *(const short8*)(pool + aRow + mt * 8192 + posA * 16);
  }

#pragma unroll 1
  for (int jt = 0; jt < 32; ++jt) {
    f32x4 acc[4][4] = {};
#pragma unroll
    for (int c = 0; c < 8; ++c) {
      const int s = jt * 8 + c;
      if (s + 1 < 256) {
        const int njt = (s + 1) >> 3, nc = (s + 1) & 7;
        stage_stream(pool + 65536 + ((s + 1) & 1) * 8192,
                     kb + (size_t)njt * 65536 + nc * 64, roff0, roff1, w);
      }
      const char* B = pool + 65536 + (s & 1) * 8192;
      short8 bfr[4];
#pragma unroll
      for (int nt = 0; nt < 4; ++nt) bfr[nt] = *(const short8*)(B + bRow + nt * 1024);
#pragma unroll
      for (int mt = 0; mt < 4; ++mt)
#pragma unroll
        for (int nt = 0; nt < 4; ++nt)
          acc[mt][nt] =
              __builtin_amdgcn_mfma_f32_16x16x32_bf16(ares[c][mt], bfr[nt], acc[mt][nt], 0, 0, 0);
      __syncthreads();
    }
    // epilogue (register-only): per-row partial sumexp over this 128-j tile
#pragma unroll
    for (int mt = 0; mt < 4; ++mt)
#pragma unroll
      for (int r = 0; r < 4; ++r) {
        float e = exp2f(acc[mt][0][r] * LOG2E - SHIFT) + exp2f(acc[mt][1][r] * LOG2E - SHIFT)
                + exp2f(acc[mt][2][r] * LOG2E - SHIFT) + exp2f(acc[mt][3][r] * LOG2E - SHIFT);
        e += __shfl_xor(e, 1); e += __shfl_xor(e, 2);
        e += __shfl_xor(e, 4); e += __shfl_xor(e, 8);
        lacc[mt][r] += e;
      }
  }
  // cross-wave reduce: alias stream-buffer area (all B reads done after final barrier)
  float* lred = (float*)(pool + 65536);
  if (ln == 0) {
#pragma unroll
    for (int mt = 0; mt < 4; ++mt)
#pragma unroll
      for (int r = 0; r < 4; ++r)
        lred[jhalf * 128 + ihalf * 64 + mt * 16 + q * 4 + r] = lacc[mt][r];
  }
  __syncthreads();
  if (t < 128) linv[b * 4096 + i0 + t] = 1.0f / (lred[t] + lred[128 + t]);
}

// ---------------------------------------------------------------------------
// K3: column sums  s_j = sum_i exp2(S_ij*log2e - 64) * linv_i.
// K-tile resident (regs); Q streams in 8KB chunks.  WG = (b, 128 k-cols).
// ---------------------------------------------------------------------------
__global__ __launch_bounds__(256, 2) void attn_colsum(
    const unsigned short* __restrict__ qt, const unsigned short* __restrict__ kt,
    const float* __restrict__ linv, float* __restrict__ s_col) {
  extern __shared__ char pool[];  // [0,64K) resident K; [64K,80K) stream Q dbuf
  const int b = blockIdx.y, j0 = blockIdx.x * 128;
  const int t = threadIdx.x, w = t >> 6, lane = t & 63, q = lane >> 4, ln = lane & 15;
  const int ihalf = w >> 1, jhalf = w & 1;
  const char* kres = (const char*)(kt + ((size_t)b * 4096 + j0) * 256);
  const char* qb = (const char*)(qt + (size_t)b * 4096 * 256);
  const int rr0 = w * 16 + (lane >> 2);
  const int gsS = (lane & 3) ^ ((lane >> 3) & 3);
  const int roff0 = rr0 * 512 + gsS * 16;
  const int roff1 = (64 + rr0) * 512 + gsS * 16;
  // fragments: A (streamed Q rows, pitch 64B), B (resident K rows, hoisted)
  const int aRow = ihalf * 4096 + ln * 64 + (q ^ ((ln >> 1) & 3)) * 16;
  const int bRow = (jhalf * 64 + ln) * 512;
  float scacc[4] = {};

  stage_resident(pool, kres, w, lane);
  stage_stream(pool + 65536, qb, roff0, roff1, w);
  __syncthreads();

  // hoist resident K fragments into registers
  short8 bres[8][4];
#pragma unroll
  for (int c = 0; c < 8; ++c) {
    const int posB = ((4 * c) & 24) | ((4 * (c & 1) + q) ^ (ln & 7));
#pragma unroll
    for (int nt = 0; nt < 4; ++nt)
      bres[c][nt] = *(const short8*)(pool + bRow + nt * 8192 + posB * 16);
  }

#pragma unroll 1
  for (int it = 0; it < 32; ++it) {
    // per-row 1/l for this q-tile (broadcast across ln; issued early)
    const float4* lp = (const float4*)(linv + (size_t)b * 4096 + it * 128 + ihalf * 64 + q * 4);
    float4 lv[4];
#pragma unroll
    for (int mt = 0; mt < 4; ++mt) lv[mt] = lp[mt * 4];

    f32x4 acc[4][4] = {};
#pragma unroll
    for (int c = 0; c < 8; ++c) {
      const int s = it * 8 + c;
      if (s + 1 < 256) {
        const int nit = (s + 1) >> 3, nc = (s + 1) & 7;
        stage_stream(pool + 65536 + ((s + 1) & 1) * 8192,
                     qb + (size_t)nit * 65536 + nc * 64, roff0, roff1, w);
      }
      const char* A = pool + 65536 + (s & 1) * 8192;
      short8 af[4];
#pragma unroll
      for (int mt = 0; mt < 4; ++mt) af[mt] = *(const short8*)(A + aRow + mt * 1024);
#pragma unroll
      for (int mt = 0; mt < 4; ++mt)
#pragma unroll
        for (int nt = 0; nt < 4; ++nt)
          acc[mt][nt] =
              __builtin_amdgcn_mfma_f32_16x16x32_bf16(af[mt], bres[c][nt], acc[mt][nt], 0, 0, 0);
      __syncthreads();
    }
#pragma unroll
    for (int nt = 0; nt < 4; ++nt) {
      float v = 0.f;
#pragma unroll
      for (int mt = 0; mt < 4; ++mt) {
        v += exp2f(acc[mt][nt][0] * LOG2E - SHIFT) * lv[mt].x;
        v += exp2f(acc[mt][nt][1] * LOG2E - SHIFT) * lv[mt].y;
        v += exp2f(acc[mt][nt][2] * LOG2E - SHIFT) * lv[mt].z;
        v += exp2f(acc[mt][nt][3] * LOG2E - SHIFT) * lv[mt].w;
      }
      v += __shfl_xor(v, 16); v += __shfl_xor(v, 32);
      scacc[nt] += v;
    }
  }
  float* sred = (float*)(pool + 65536);
  if (q == 0) {
#pragma unroll
    for (int nt = 0; nt < 4; ++nt)
      sred[ihalf * 128 + jhalf * 64 + nt * 16 + ln] = scacc[nt];
  }
  __syncthreads();
  if (t < 128) s_col[b * 4096 + j0 + t] = sred[t] + sred[128 + t];
}

// ---------------------------------------------------------------------------
// K1 v2: projection  Out[b][sp][co] = sum_ci In[b][ci][sp]*W[co][ci] + bias[co]
// 128 sp x 256 co tile, 4 waves each 64sp x 2x64co (acc[2][4][4]).
// ---------------------------------------------------------------------------
__global__ __launch_bounds__(256, 2) void proj2_kernel(
    const float* __restrict__ In, const unsigned short* __restrict__ Wbf,
    const float* __restrict__ bias, unsigned short* __restrict__ Out, int Kdim) {
  __shared__ char Alds[128 * 144];   // 18 KB
  __shared__ char Blds[256 * 128];   // 32 KB
  const int b = blockIdx.y, sp0 = blockIdx.x * 128;
  const int t = threadIdx.x, w = t >> 6, lane = t & 63, q = lane >> 4, ln = lane & 15;
  const int shalf = w >> 1;          // sp half (0..1)
  const int cq = w & 1;              // co quarter-within-half (0..1)
  const size_t wrow = (size_t)Kdim * 2;  // W row stride in bytes
  f32x4 acc[2][4][4] = {};
  const int nch = Kdim >> 6;

  const int brow0 = w * 8 + (lane >> 3);            // + i*32 per issue
  const int bgs = (lane & 7) ^ (lane >> 3);
  const int cp = t >> 3;             // ci pair 0..31
  const int spg = t & 7;             // sp group of 16

#pragma unroll 1
  for (int ch = 0; ch < nch; ++ch) {
    const int ci0 = ch * 64;
    // ---- stage B: W[256 co][64 ci] via global_load_lds, swizzled source ----
    const char* wsrc = (const char*)Wbf + (size_t)ci0 * 2 + bgs * 16;
#pragma unroll
    for (int i = 0; i < 8; ++i)
      gl2lds16(wsrc + (size_t)(brow0 + i * 32) * wrow, Blds + i * 4096 + w * 1024);
    // ---- stage A: transpose-convert In[64 ci][128 sp] -> Alds[sp][ci] ----
    {
      const float* r0 = In + ((size_t)b * Kdim + ci0 + 2 * cp) * 4096 + sp0 + spg * 16;
      const float* r1 = r0 + 4096;
#pragma unroll
      for (int h = 0; h < 2; ++h) {
        float4 a0 = *(const float4*)(r0 + h * 8);
        float4 a1 = *(const float4*)(r0 + h * 8 + 4);
        float4 b0 = *(const float4*)(r1 + h * 8);
        float4 b1 = *(const float4*)(r1 + h * 8 + 4);
        float va[8] = {a0.x, a0.y, a0.z, a0.w, a1.x, a1.y, a1.z, a1.w};
        float vb[8] = {b0.x, b0.y, b0.z, b0.w, b1.x, b1.y, b1.z, b1.w};
#pragma unroll
        for (int e = 0; e < 8; ++e) {
          const int spl = spg * 16 + h * 8 + e;
          const int colb = (cp << 2) ^ (((spl >> 4) & 7) << 4);
          unsigned u0 = f2bf(va[e]), u1 = f2bf(vb[e]);
          *(unsigned*)(Alds + spl * 144 + colb) = u0 | (u1 << 16);
        }
      }
    }
    __syncthreads();
    // ---- MFMA: 2 ks x (4 A-frags, 2 co-halves x 4 B-frags x 16 mfma) ----
#pragma unroll
    for (int ks = 0; ks < 2; ++ks) {
      short8 af[4], bfr[4];
#pragma unroll
      for (int mt = 0; mt < 4; ++mt) {
        const int row = shalf * 64 + mt * 16 + ln;
        const int colr = (ks * 64 + q * 16) ^ (((row >> 4) & 7) << 4);
        af[mt] = *(const short8*)(Alds + row * 144 + colr);
      }
#pragma unroll
      for (int cb = 0; cb < 2; ++cb) {
#pragma unroll
        for (int nt = 0; nt < 4; ++nt) {
          const int row = cb * 128 + cq * 64 + nt * 16 + ln;
          const int pos = (ks * 4 + q) ^ (ln & 7);
          bfr[nt] = *(const short8*)(Blds + row * 128 + pos * 16);
        }
#pragma unroll
        for (int mt = 0; mt < 4; ++mt)
#pragma unroll
          for (int nt = 0; nt < 4; ++nt)
            acc[cb][mt][nt] =
                __builtin_amdgcn_mfma_f32_16x16x32_bf16(af[mt], bfr[nt], acc[cb][mt][nt], 0, 0, 0);
      }
    }
    __syncthreads();
  }
  // ---- epilogue ----
#pragma unroll
  for (int cb = 0; cb < 2; ++cb)
#pragma unroll
    for (int nt = 0; nt < 4; ++nt) {
      const int co = cb * 128 + cq * 64 + nt * 16 + ln;
      const float bv = bias[co];
#pragma unroll
      for (int mt = 0; mt < 4; ++mt)
#pragma unroll
        for (int r = 0; r < 4; ++r) {
          const int sp = sp0 + shalf * 64 + mt * 16 + q * 4 + r;
          Out[((size_t)b * 4096 + sp) * 256 + co] = f2bf(acc[cb][mt][nt][r] + bv);
        }
    }
}

// ---------------------------------------------------------------------------
// sbar[b] = sum_n s[b][n] / 4096
// ---------------------------------------------------------------------------
__global__ void sbar_kernel(const float* __restrict__ s_col, float* __restrict__ sbar) {
  const int b = blockIdx.x, t = threadIdx.x;
  float v = 0.f;
  for (int k = 0; k < 16; ++k) v += s_col[b * 4096 + t + 256 * k];
  for (int m = 1; m < 64; m <<= 1) v += __shfl_xor(v, m);
  __shared__ float red[4];
  if ((t & 63) == 0) red[t >> 6] = v;
  __syncthreads();
  if (t == 0) sbar[b] = (red[0] + red[1] + red[2] + red[3]) * (1.f / 4096.f);
}

// ---------------------------------------------------------------------------
// K4 v2: pooling, one wave = one contiguous channel row (fully coalesced).
// ---------------------------------------------------------------------------
__global__ __launch_bounds__(256) void pool2_kernel(
    const float* __restrict__ img, const float* __restrict__ pc2d,
    const float* __restrict__ s_col, float* __restrict__ u_pool,
    float* __restrict__ imean, float* __restrict__ t_pool) {
  const int t = threadIdx.x, w = t >> 6, lane = t & 63;
  const int gid = blockIdx.x * 4 + w;
  const int b = gid / 2304, c = gid - b * 2304;
  const bool isimg = c < 256;
  const float4* row4 = isimg
      ? (const float4*)(img + ((size_t)b * 256 + c) * 4096)
      : (const float4*)(pc2d + ((size_t)b * 2048 + (c - 256)) * 4096);
  const float4* s4 = (const float4*)(s_col + (size_t)b * 4096);
  float accd = 0.f, accs = 0.f;
#pragma unroll
  for (int kk = 0; kk < 16; ++kk) {
    float4 x = row4[lane + 64 * kk];
    float4 sv = s4[lane + 64 * kk];
    accd += x.x * sv.x + x.y * sv.y + x.z * sv.z + x.w * sv.w;
    accs += x.x + x.y + x.z + x.w;
  }
#pragma unroll
  for (int m = 1; m < 64; m <<= 1) {
    accd += __shfl_xor(accd, m);
    accs += __shfl_xor(accs, m);
  }
  if (lane == 0) {
    if (isimg) {
      u_pool[b * 256 + c] = accd * (1.f / 4096.f);
      imean[b * 256 + c] = accs * (1.f / 4096.f);
    } else {
      t_pool[b * 2048 + (c - 256)] = accd * (1.f / 4096.f);
    }
  }
}

// ---------------------------------------------------------------------------
// img_feat -> fused[0:256]
// ---------------------------------------------------------------------------
__global__ void imgfeat_kernel(const float* __restrict__ Wvi, const float* __restrict__ bvi,
                               const float* __restrict__ gamma1, const float* __restrict__ u_pool,
                               const float* __restrict__ imean, const float* __restrict__ sbar,
                               float* __restrict__ fused) {
  const int t = threadIdx.x;
  const int co = blockIdx.x * 64 + (t >> 2), j = t & 3;
  float acc[16];
#pragma unroll
  for (int b = 0; b < 16; ++b) acc[b] = 0.f;
  const float4* w4 = (const float4*)(Wvi + (size_t)co * 256);
  for (int kk = 0; kk < 16; ++kk) {
    float4 wv = w4[j + 4 * kk];
#pragma unroll
    for (int b = 0; b < 16; ++b) {
      float4 uv = ((const float4*)(u_pool + b * 256))[j + 4 * kk];
      acc[b] += wv.x * uv.x + wv.y * uv.y + wv.z * uv.z + wv.w * uv.w;
    }
  }
#pragma unroll
  for (int b = 0; b < 16; ++b) { acc[b] += __shfl_xor(acc[b], 1); acc[b] += __shfl_xor(acc[b], 2); }
  if (j == 0) {
    float g = gamma1[0], bv = bvi[co];
#pragma unroll
    for (int b = 0; b < 16; ++b)
      fused[b * 2304 + co] = g * (acc[b] + bv * sbar[b]) + imean[b * 256 + co];
  }
}

// ---------------------------------------------------------------------------
// pc_feat -> fused[256:2304]
// ---------------------------------------------------------------------------
__global__ void pcfeat_kernel(const float* __restrict__ Wvp, const float* __restrict__ bvp,
                              const float* __restrict__ t_pool, const float* __restrict__ sbar,
                              float* __restrict__ fused) {
  const int t = threadIdx.x;
  const int co = blockIdx.x * 64 + (t >> 2), j = t & 3;
  float acc[16];
#pragma unroll
  for (int b = 0; b < 16; ++b) acc[b] = 0.f;
  const float4* w4 = (const float4*)(Wvp + (size_t)co * 2048);
  for (int kk = 0; kk < 128; ++kk) {
    float4 wv = w4[j + 4 * kk];
#pragma unroll
    for (int b = 0; b < 16; ++b) {
      float4 tv = ((const float4*)(t_pool + b * 2048))[j + 4 * kk];
      acc[b] += wv.x * tv.x + wv.y * tv.y + wv.z * tv.z + wv.w * tv.w;
    }
  }
#pragma unroll
  for (int b = 0; b < 16; ++b) { acc[b] += __shfl_xor(acc[b], 1); acc[b] += __shfl_xor(acc[b], 2); }
  if (j == 0) {
    float bv = bvp[co];
#pragma unroll
    for (int b = 0; b < 16; ++b)
      fused[b * 2304 + 256 + co] = acc[b] + bv * sbar[b];
  }
}

// ---------------------------------------------------------------------------
// h = relu(fused @ W1^T + b1)
// ---------------------------------------------------------------------------
__global__ void head1_kernel(const float* __restrict__ W1, const float* __restrict__ b1,
                             const float* __restrict__ fused, float* __restrict__ h) {
  const int t = threadIdx.x;
  const int o = blockIdx.x * 64 + (t >> 2), j = t & 3;
  float acc[16];
#pragma unroll
  for (int b = 0; b < 16; ++b) acc[b] = 0.f;
  const float4* w4 = (const float4*)(W1 + (size_t)o * 2304);
  for (int kk = 0; kk < 144; ++kk) {
    float4 wv = w4[j + 4 * kk];
#pragma unroll
    for (int b = 0; b < 16; ++b) {
      float4 fv = ((const float4*)(fused + b * 2304))[j + 4 * kk];
      acc[b] += wv.x * fv.x + wv.y * fv.y + wv.z * fv.z + wv.w * fv.w;
    }
  }
#pragma unroll
  for (int b = 0; b < 16; ++b) { acc[b] += __shfl_xor(acc[b], 1); acc[b] += __shfl_xor(acc[b], 2); }
  if (j == 0) {
    float bv = b1[o];
#pragma unroll
    for (int b = 0; b < 16; ++b) h[b * 1024 + o] = fmaxf(acc[b] + bv, 0.f);
  }
}

// ---------------------------------------------------------------------------
// logits + log_softmax -> out[b][40]
// ---------------------------------------------------------------------------
__global__ void head2_kernel(const float* __restrict__ W2, const float* __restrict__ b2,
                             const float* __restrict__ h, float* __restrict__ out) {
  const int b = blockIdx.x, t = threadIdx.x;
  __shared__ float logit[40];
  __shared__ float red[4];
  float4 hv = ((const float4*)(h + b * 1024))[t];
  for (int c = 0; c < 40; ++c) {
    float4 wv = ((const float4*)(W2 + (size_t)c * 1024))[t];
    float p = wv.x * hv.x + wv.y * hv.y + wv.z * hv.z + wv.w * hv.w;
    for (int m = 1; m < 64; m <<= 1) p += __shfl_xor(p, m);
    if ((t & 63) == 0) red[t >> 6] = p;
    __syncthreads();
    if (t == 0) logit[c] = red[0] + red[1] + red[2] + red[3] + b2[c];
    __syncthreads();
  }
  if (t == 0) {
    float mx = -1e30f;
    for (int c = 0; c < 40; ++c) mx = fmaxf(mx, logit[c]);
    float s = 0.f;
    for (int c = 0; c < 40; ++c) s += expf(logit[c] - mx);
    float ls = logf(s);
    for (int c = 0; c < 40; ++c) out[b * 40 + c] = logit[c] - mx - ls;
  }
}

// ---------------------------------------------------------------------------
extern "C" void kernel_launch(void* const* d_in, const int* in_sizes, int n_in,
                              void* d_out, int out_size, void* d_ws, size_t ws_size,
                              hipStream_t stream) {
  (void)in_sizes; (void)n_in; (void)out_size; (void)ws_size;
  const float* img    = (const float*)d_in[0];
  const float* pc2d   = (const float*)d_in[1];
  const float* Wq     = (const float*)d_in[2];
  const float* bq     = (const float*)d_in[3];
  const float* Wk     = (const float*)d_in[4];
  const float* bk     = (const float*)d_in[5];
  const float* Wvi    = (const float*)d_in[6];
  const float* bvi    = (const float*)d_in[7];
  const float* Wvp    = (const float*)d_in[8];
  const float* bvp    = (const float*)d_in[9];
  const float* gamma1 = (const float*)d_in[10];
  const float* W1     = (const float*)d_in[11];
  const float* b1     = (const float*)d_in[12];
  const float* W2     = (const float*)d_in[13];
  const float* b2     = (const float*)d_in[14];

  char* ws = (char*)d_ws;
  unsigned short* q_t   = (unsigned short*)(ws + 0);          // 32 MB
  unsigned short* k_t   = (unsigned short*)(ws + 33554432);   // 32 MB
  unsigned short* wq_bf = (unsigned short*)(ws + 67108864);   // 128 KB
  unsigned short* wk_bf = (unsigned short*)(ws + 67239936);   // 1 MB
  float* linv   = (float*)(ws + 68288512);                    // 16*4096 f32
  float* s_col  = (float*)(ws + 68812800);
  float* sbar   = (float*)(ws + 69074944);
  float* u_pool = (float*)(ws + 69075008);
  float* imean  = (float*)(ws + 69091392);
  float* t_pool = (float*)(ws + 69107776);
  float* fusedb = (float*)(ws + 69238848);
  float* h_buf  = (float*)(ws + 69386304);

  // enable 80 KiB dynamic LDS for the attention kernels (2 blocks/CU = 160 KiB)
  hipFuncSetAttribute((const void*)attn_rowsum, hipFuncAttributeMaxDynamicSharedMemorySize, 81920);
  hipFuncSetAttribute((const void*)attn_colsum, hipFuncAttributeMaxDynamicSharedMemorySize, 81920);

  cvt_bf16_2<<<dim3(576), dim3(256), 0, stream>>>(Wq, wq_bf, Wk, wk_bf);

  proj2_kernel<<<dim3(32, 16), dim3(256), 0, stream>>>(img, wq_bf, bq, q_t, 256);
  proj2_kernel<<<dim3(32, 16), dim3(256), 0, stream>>>(pc2d, wk_bf, bk, k_t, 2048);

  attn_rowsum<<<dim3(32, 16), dim3(256), 81920, stream>>>(q_t, k_t, linv);
  attn_colsum<<<dim3(32, 16), dim3(256), 81920, stream>>>(q_t, k_t, linv, s_col);

  sbar_kernel<<<dim3(16), dim3(256), 0, stream>>>(s_col, sbar);
  pool2_kernel<<<dim3(9216), dim3(256), 0, stream>>>(img, pc2d, s_col, u_pool, imean, t_pool);

  imgfeat_kernel<<<dim3(4), dim3(256), 0, stream>>>(Wvi, bvi, gamma1, u_pool, imean, sbar, fusedb);
  pcfeat_kernel<<<dim3(32), dim3(256), 0, stream>>>(Wvp, bvp, t_pool, sbar, fusedb);

  head1_kernel<<<dim3(16), dim3(256), 0, stream>>>(W1, b1, fusedb, h_buf);
  head2_kernel<<<dim3(16), dim3(256), 0, stream>>>(W2, b2, h_buf, (float*)d_out);
}